// Round 1
// baseline (430.309 us; speedup 1.0000x reference)
//
#include <hip/hip_runtime.h>

// VectorQuantizer: x (32,64,64,64) f32, codebook (1024,64) f32
// out = concat( quantized (32,64,64,64) f32 , indices (32,64,64) as f32 )
//
// Strategy R1: exact-f32 VALU baseline. 1 thread = 1 spatial position.
// Codebook rows are wave-uniform in the K loop -> scalar loads (SGPR) + FMA.
// argmin(cb_norm[k] - 2*dot) with strict < (first-min tie-break, matches jnp).

#define VQ_D   64
#define VQ_K   1024
#define VQ_HW  4096        // 64*64 spatial per batch
#define VQ_B   32
#define VQ_NPOS (VQ_B * VQ_HW)   // 131072

__global__ __launch_bounds__(256, 2)
void vq_argmin_kernel(const float* __restrict__ x,
                      const float* __restrict__ cb,
                      float* __restrict__ out,       // (B,D,H,W)
                      float* __restrict__ idx_out)   // (B,H,W) as float
{
    __shared__ float cbn[VQ_K];
    const int tid = threadIdx.x;

    // ---- codebook norms into LDS (once per block, ~0.4% of FLOPs) ----
    for (int k = tid; k < VQ_K; k += 256) {
        const float* row = cb + k * VQ_D;
        float a0 = 0.f, a1 = 0.f, a2 = 0.f, a3 = 0.f;
        #pragma unroll
        for (int d = 0; d < VQ_D; d += 4) {
            float4 c = *(const float4*)(row + d);
            a0 = fmaf(c.x, c.x, a0);
            a1 = fmaf(c.y, c.y, a1);
            a2 = fmaf(c.z, c.z, a2);
            a3 = fmaf(c.w, c.w, a3);
        }
        cbn[k] = (a0 + a1) + (a2 + a3);
    }
    __syncthreads();

    // ---- load this thread's 64-dim x vector (coalesced per-d) ----
    const int p = blockIdx.x * 256 + tid;     // global position
    const int b = p >> 12;                    // 4096 positions per batch
    const int n = p & (VQ_HW - 1);
    const float* xp = x + b * (VQ_D * VQ_HW) + n;

    float xr[VQ_D];
    #pragma unroll
    for (int d = 0; d < VQ_D; ++d) xr[d] = xp[d * VQ_HW];

    // ---- argmin over K=1024 codes; codebook access is wave-uniform ----
    float best = 3.4e38f;
    int bestk = 0;
    for (int k = 0; k < VQ_K; ++k) {
        const float* row = cb + k * VQ_D;     // uniform -> scalar loads
        float a0 = 0.f, a1 = 0.f, a2 = 0.f, a3 = 0.f;
        #pragma unroll
        for (int d = 0; d < VQ_D; d += 4) {
            a0 = fmaf(xr[d + 0], row[d + 0], a0);
            a1 = fmaf(xr[d + 1], row[d + 1], a1);
            a2 = fmaf(xr[d + 2], row[d + 2], a2);
            a3 = fmaf(xr[d + 3], row[d + 3], a3);
        }
        float dot  = (a0 + a1) + (a2 + a3);
        float dist = cbn[k] - 2.0f * dot;
        if (dist < best) { best = dist; bestk = k; }   // strict <: first min
    }

    // ---- epilogue: gather winning row, scatter to (B,D,H,W) layout ----
    float* op = out + b * (VQ_D * VQ_HW) + n;
    const float* wrow = cb + bestk * VQ_D;    // divergent gather (L2-hot)
    #pragma unroll
    for (int d = 0; d < VQ_D; ++d) op[d * VQ_HW] = wrow[d];

    idx_out[p] = (float)bestk;
}

extern "C" void kernel_launch(void* const* d_in, const int* in_sizes, int n_in,
                              void* d_out, int out_size, void* d_ws, size_t ws_size,
                              hipStream_t stream) {
    const float* x  = (const float*)d_in[0];
    const float* cb = (const float*)d_in[1];
    float* out = (float*)d_out;
    float* idx = out + (size_t)VQ_B * VQ_D * VQ_HW;   // 8,388,608 floats in

    vq_argmin_kernel<<<dim3(VQ_NPOS / 256), dim3(256), 0, stream>>>(x, cb, out, idx);
}